// Round 2
// baseline (1006.479 us; speedup 1.0000x reference)
//
#include <hip/hip_runtime.h>
#include <stdint.h>

// B=2, L=2048, D=512, H=8, DK=DV=64, TEMP=8, LN_EPS=1e-5

typedef float fx4 __attribute__((ext_vector_type(4)));
typedef short bfx8 __attribute__((ext_vector_type(8)));
typedef short sx4 __attribute__((ext_vector_type(4)));

#define MFMA16(a, b, c) __builtin_amdgcn_mfma_f32_16x16x32_bf16((a), (b), (c), 0, 0, 0)

__device__ __forceinline__ unsigned short f2bf(float f) {
  union { float f; uint32_t u; } v; v.f = f;
  uint32_t r = v.u + 0x7FFFu + ((v.u >> 16) & 1u);  // RNE
  return (unsigned short)(r >> 16);
}

__device__ __forceinline__ bfx8 ldbf8(const unsigned short* p) {
  return *reinterpret_cast<const bfx8*>(p);
}

__device__ __forceinline__ bfx8 cvt8(const float* p) {
  fx4 a = *reinterpret_cast<const fx4*>(p);
  fx4 b = *reinterpret_cast<const fx4*>(p + 4);
  bfx8 r;
  r[0] = (short)f2bf(a[0]); r[1] = (short)f2bf(a[1]);
  r[2] = (short)f2bf(a[2]); r[3] = (short)f2bf(a[3]);
  r[4] = (short)f2bf(b[0]); r[5] = (short)f2bf(b[1]);
  r[6] = (short)f2bf(b[2]); r[7] = (short)f2bf(b[3]);
  return r;
}

// ---------------- kernel 0a: convert 4 weight matrices (512x512 f32) to bf16 ----
__global__ __launch_bounds__(256) void k_w2bf(const float* __restrict__ s0,
                                              const float* __restrict__ s1,
                                              const float* __restrict__ s2,
                                              const float* __restrict__ s3,
                                              unsigned short* __restrict__ dst) {
  int y = blockIdx.y;
  const float* s = (y == 0) ? s0 : (y == 1) ? s1 : (y == 2) ? s2 : s3;
  int i = (blockIdx.x * 256 + threadIdx.x) * 4;
  fx4 v = *reinterpret_cast<const fx4*>(s + i);
  sx4 o;
  o[0] = (short)f2bf(v[0]); o[1] = (short)f2bf(v[1]);
  o[2] = (short)f2bf(v[2]); o[3] = (short)f2bf(v[3]);
  *reinterpret_cast<sx4*>(dst + y * 262144 + i) = o;
}

// ---------------- kernel 0b: pack int mask -> bitmask -----------------------------
__global__ __launch_bounds__(256) void k_maskpack(const int* __restrict__ mask,
                                                  unsigned long long* __restrict__ mbits) {
  int i = blockIdx.x * 256 + threadIdx.x;  // total 8388608
  unsigned long long b = __ballot(mask[i] != 0);
  if ((threadIdx.x & 63) == 0) mbits[i >> 6] = b;
}

// ---------------- kernel 1: fused QKV projection with LDS-staged A ---------------
// z=0: Q -> Qb [bh][l][64]; z=1: K -> Kb same; z=2: V -> Vt [bh][64][l] (transposed)
#define XPITCH2 40
__global__ __launch_bounds__(256) void k_proj2(const float* __restrict__ qin,
                                               const float* __restrict__ kin,
                                               const float* __restrict__ vin,
                                               const unsigned short* __restrict__ Wb,
                                               const float* __restrict__ b_qs,
                                               const float* __restrict__ b_ks,
                                               const float* __restrict__ b_vs,
                                               unsigned short* __restrict__ Qb,
                                               unsigned short* __restrict__ Kbo,
                                               unsigned short* __restrict__ Vt) {
  __shared__ unsigned short Xs[64 * XPITCH2];  // 64 rows x 32 k bf16, pitch 40
  int z = blockIdx.z;
  const float* X = (z == 0) ? qin : (z == 1) ? kin : vin;
  const unsigned short* W = Wb + z * 262144;
  const float* bias = (z == 0) ? b_qs : (z == 1) ? b_ks : b_vs;
  unsigned short* dst = (z == 0) ? Qb : (z == 1) ? Kbo : Vt;

  int wave = threadIdx.x >> 6, lane = threadIdx.x & 63;
  int quad = lane >> 4, tn = lane & 15;
  int mblk = blockIdx.x * 64;
  int m0 = mblk + wave * 16;
  int n0 = blockIdx.y * 64;
  int srow = threadIdx.x >> 2;        // 0..63
  int skc = (threadIdx.x & 3) * 8;    // 0,8,16,24

  fx4 acc[4];
  #pragma unroll
  for (int i = 0; i < 4; ++i) acc[i] = (fx4){0.f, 0.f, 0.f, 0.f};

  for (int k0 = 0; k0 < 512; k0 += 32) {
    bfx8 xa = cvt8(X + (size_t)(mblk + srow) * 512 + k0 + skc);  // coalesced 32B/thr
    *reinterpret_cast<bfx8*>(&Xs[srow * XPITCH2 + skc]) = xa;
    __syncthreads();
    bfx8 af = ldbf8(&Xs[(wave * 16 + tn) * XPITCH2 + quad * 8]);
    #pragma unroll
    for (int nt = 0; nt < 4; ++nt) {
      const unsigned short* wp = W + (size_t)(n0 + nt * 16 + tn) * 512 + k0 + quad * 8;
      acc[nt] = MFMA16(af, ldbf8(wp), acc[nt]);
    }
    __syncthreads();
  }

  #pragma unroll
  for (int nt = 0; nt < 4; ++nt) {
    int n = n0 + nt * 16 + tn;
    int h = n >> 6, dd = n & 63;
    float bv = bias[n];
    if (z == 2) {
      int r0 = m0 + quad * 4;
      int bb = r0 >> 11, l = r0 & 2047;
      sx4 o;
      #pragma unroll
      for (int i = 0; i < 4; ++i) o[i] = (short)f2bf(acc[nt][i] + bv);
      unsigned short* vp = dst + (size_t)((bb * 8 + h) * 64 + dd) * 2048 + l;
      *reinterpret_cast<sx4*>(vp) = o;
    } else {
      #pragma unroll
      for (int i = 0; i < 4; ++i) {
        int r = m0 + quad * 4 + i;
        int bb = r >> 11, l = r & 2047;
        dst[(size_t)((bb * 8 + h) * 2048 + l) * 64 + dd] = f2bf(acc[nt][i] + bv);
      }
    }
  }
}

// ---------------- kernel 2a: scores + softmax, S strip in REGISTERS --------------
// block = 512 thr (8 waves); wave w owns keys [w*256, w*256+256), 16 q rows.
__global__ __launch_bounds__(512, 4) void k_score(const unsigned short* __restrict__ Qb,
                                                  const unsigned short* __restrict__ Kb,
                                                  const float* __restrict__ gate,
                                                  const unsigned long long* __restrict__ mbits,
                                                  float* __restrict__ attn_out) {
  __shared__ float redm[8][16];
  __shared__ float reds[8][16];
  int wave = threadIdx.x >> 6, lane = threadIdx.x & 63;
  int quad = lane >> 4, tn = lane & 15;
  int q0 = blockIdx.x * 16;
  int bh = blockIdx.y;
  int b = bh >> 3;
  int key_base = wave * 256;

  // Q fragments (same 16 q-rows for all waves)
  const unsigned short* Qbase = Qb + ((size_t)bh * 2048 + q0) * 64;
  bfx8 aq0 = ldbf8(Qbase + tn * 64 + quad * 8);
  bfx8 aq1 = ldbf8(Qbase + tn * 64 + 32 + quad * 8);

  // S = Q K^T for this wave's 256 keys: 16 fragments in registers
  const unsigned short* Kbase = Kb + (size_t)bh * 2048 * 64;
  fx4 S[16];
  #pragma unroll
  for (int kt = 0; kt < 16; ++kt) {
    const unsigned short* kp = Kbase + (size_t)(key_base + kt * 16 + tn) * 64 + quad * 8;
    fx4 d = (fx4){0.f, 0.f, 0.f, 0.f};
    d = MFMA16(aq0, ldbf8(kp), d);
    d = MFMA16(aq1, ldbf8(kp + 32), d);
    S[kt] = d;
  }

  // gate * mask, track row max
  const float* gbase = gate + (((size_t)bh * 2048 + q0) * 2048) + key_base;
  const unsigned long long* mbase = mbits + ((size_t)(b * 2048 + q0)) * 32 + wave * 4;
  float lmax[4] = {-3.0e38f, -3.0e38f, -3.0e38f, -3.0e38f};
  #pragma unroll
  for (int kt4 = 0; kt4 < 4; ++kt4) {
    unsigned long long mw[4];
    #pragma unroll
    for (int i = 0; i < 4; ++i) mw[i] = mbase[(quad * 4 + i) * 32 + kt4];
    #pragma unroll
    for (int j = 0; j < 4; ++j) {
      int kt = kt4 * 4 + j;
      int koff = kt * 16 + tn;
      #pragma unroll
      for (int i = 0; i < 4; ++i) {
        float g = gbase[(size_t)(quad * 4 + i) * 2048 + koff];
        float v = S[kt][i] * 0.125f * g;
        if ((mw[i] >> (j * 16 + tn)) & 1ull) v = -3.0e38f;
        S[kt][i] = v;
        lmax[i] = fmaxf(lmax[i], v);
      }
    }
  }

  // row max: cross-lane over tn, then cross-wave via LDS
  #pragma unroll
  for (int i = 0; i < 4; ++i) {
    float m = lmax[i];
    m = fmaxf(m, __shfl_xor(m, 1));
    m = fmaxf(m, __shfl_xor(m, 2));
    m = fmaxf(m, __shfl_xor(m, 4));
    m = fmaxf(m, __shfl_xor(m, 8));
    if (tn == 0) redm[wave][quad * 4 + i] = m;
  }
  __syncthreads();
  float gmax[4];
  #pragma unroll
  for (int i = 0; i < 4; ++i) {
    float m = -3.0e38f;
    #pragma unroll
    for (int jw = 0; jw < 8; ++jw) m = fmaxf(m, redm[jw][quad * 4 + i]);
    gmax[i] = m;
  }

  // exp + row sum
  float lsum[4] = {0.f, 0.f, 0.f, 0.f};
  #pragma unroll
  for (int kt = 0; kt < 16; ++kt) {
    #pragma unroll
    for (int i = 0; i < 4; ++i) {
      float p = __expf(S[kt][i] - gmax[i]);
      S[kt][i] = p;
      lsum[i] += p;
    }
  }
  #pragma unroll
  for (int i = 0; i < 4; ++i) {
    float s = lsum[i];
    s += __shfl_xor(s, 1);
    s += __shfl_xor(s, 2);
    s += __shfl_xor(s, 4);
    s += __shfl_xor(s, 8);
    if (tn == 0) reds[wave][quad * 4 + i] = s;
  }
  __syncthreads();
  float inv[4];
  #pragma unroll
  for (int i = 0; i < 4; ++i) {
    float s = 0.f;
    #pragma unroll
    for (int jw = 0; jw < 8; ++jw) s += reds[jw][quad * 4 + i];
    inv[i] = 1.0f / s;
  }

  // store normalized attention
  float* obase = attn_out + (((size_t)bh * 2048 + q0) * 2048) + key_base;
  #pragma unroll
  for (int kt = 0; kt < 16; ++kt) {
    #pragma unroll
    for (int i = 0; i < 4; ++i)
      obase[(size_t)(quad * 4 + i) * 2048 + kt * 16 + tn] = S[kt][i] * inv[i];
  }
}

// ---------------- kernel 2b: O = attn @ V (streaming GEMM, LDS-staged A) ---------
#define APITCH 72
__global__ __launch_bounds__(256) void k_pv(const float* __restrict__ attn,
                                            const unsigned short* __restrict__ Vt,
                                            unsigned short* __restrict__ Ob) {
  __shared__ unsigned short Abuf[32 * APITCH];  // 32 q-rows x 64 keys bf16, pitch 72
  int wave = threadIdx.x >> 6, lane = threadIdx.x & 63;
  int quad = lane >> 4, tn = lane & 15;
  int q0 = blockIdx.x * 32;
  int bh = blockIdx.y;
  int b = bh >> 3, h = bh & 7;
  int r0 = (wave & 1) * 16;       // row group within 32-row tile
  int n0w = (wave >> 1) * 32;     // dv half

  const float* abase = attn + ((size_t)bh * 2048 + q0) * 2048;
  const unsigned short* vbase = Vt + (size_t)bh * 64 * 2048;
  int srow = threadIdx.x >> 3;        // 0..31
  int skc = (threadIdx.x & 7) * 8;    // 0..56

  fx4 acc[2];
  acc[0] = (fx4){0.f, 0.f, 0.f, 0.f};
  acc[1] = (fx4){0.f, 0.f, 0.f, 0.f};

  for (int kc = 0; kc < 32; ++kc) {
    int k0 = kc * 64;
    bfx8 xa = cvt8(abase + (size_t)srow * 2048 + k0 + skc);  // coalesced 32B/thr
    *reinterpret_cast<bfx8*>(&Abuf[srow * APITCH + skc]) = xa;
    __syncthreads();
    #pragma unroll
    for (int j = 0; j < 2; ++j) {
      bfx8 af = ldbf8(&Abuf[(r0 + tn) * APITCH + j * 32 + quad * 8]);
      #pragma unroll
      for (int nt = 0; nt < 2; ++nt) {
        bfx8 bv = ldbf8(vbase + (size_t)(n0w + nt * 16 + tn) * 2048 + k0 + j * 32 + quad * 8);
        acc[nt] = MFMA16(af, bv, acc[nt]);
      }
    }
    __syncthreads();
  }

  #pragma unroll
  for (int nt = 0; nt < 2; ++nt) {
    #pragma unroll
    for (int i = 0; i < 4; ++i) {
      int r = q0 + r0 + quad * 4 + i;
      Ob[(size_t)(b * 2048 + r) * 512 + h * 64 + n0w + nt * 16 + tn] = f2bf(acc[nt][i]);
    }
  }
}

// ---------------- kernel 3: FC + bias + residual + LayerNorm ---------------------
#define XPITCH 516
__global__ __launch_bounds__(256) void k_fc_ln(const unsigned short* __restrict__ Ob,
                                               const unsigned short* __restrict__ Wfcb,
                                               const float* __restrict__ bfc,
                                               const float* __restrict__ resid,
                                               const float* __restrict__ lng,
                                               const float* __restrict__ lnb,
                                               float* __restrict__ out) {
  __shared__ float xb[16 * XPITCH];
  int wave = threadIdx.x >> 6, lane = threadIdx.x & 63;
  int quad = lane >> 4, tn = lane & 15;
  int m0 = blockIdx.x * 16;

  fx4 acc[8];
  #pragma unroll
  for (int i = 0; i < 8; ++i) acc[i] = (fx4){0.f, 0.f, 0.f, 0.f};

  const unsigned short* arow = Ob + (size_t)(m0 + tn) * 512;
  for (int k0 = 0; k0 < 512; k0 += 32) {
    bfx8 af = ldbf8(arow + k0 + quad * 8);
    #pragma unroll
    for (int nt = 0; nt < 8; ++nt) {
      const unsigned short* wp = Wfcb + (size_t)(wave * 128 + nt * 16 + tn) * 512 + k0 + quad * 8;
      acc[nt] = MFMA16(af, ldbf8(wp), acc[nt]);
    }
  }
  #pragma unroll
  for (int nt = 0; nt < 8; ++nt) {
    int col = wave * 128 + nt * 16 + tn;
    #pragma unroll
    for (int i = 0; i < 4; ++i) xb[(quad * 4 + i) * XPITCH + col] = acc[nt][i];
  }
  __syncthreads();

  #pragma unroll
  for (int ri = 0; ri < 4; ++ri) {
    int r = wave * 4 + ri;
    int row = m0 + r;
    float* xr = xb + r * XPITCH;
    const float* qr = resid + (size_t)row * 512;
    float sum = 0.f, sq = 0.f;
    #pragma unroll
    for (int it = 0; it < 2; ++it) {
      int i4 = lane + it * 64;
      fx4 x = *reinterpret_cast<fx4*>(xr + i4 * 4);
      fx4 bb = *reinterpret_cast<const fx4*>(bfc + i4 * 4);
      fx4 rr = *reinterpret_cast<const fx4*>(qr + i4 * 4);
      x = x + bb + rr;
      *reinterpret_cast<fx4*>(xr + i4 * 4) = x;
      sum += x[0] + x[1] + x[2] + x[3];
      sq  += x[0]*x[0] + x[1]*x[1] + x[2]*x[2] + x[3]*x[3];
    }
    #pragma unroll
    for (int off = 32; off; off >>= 1) {
      sum += __shfl_xor(sum, off);
      sq  += __shfl_xor(sq, off);
    }
    float mu = sum * (1.f / 512.f);
    float var = sq * (1.f / 512.f) - mu * mu;
    float rstd = rsqrtf(var + 1e-5f);
    #pragma unroll
    for (int it = 0; it < 2; ++it) {
      int i4 = lane + it * 64;
      fx4 x = *reinterpret_cast<fx4*>(xr + i4 * 4);
      fx4 gg = *reinterpret_cast<const fx4*>(lng + i4 * 4);
      fx4 be = *reinterpret_cast<const fx4*>(lnb + i4 * 4);
      fx4 y = (x - mu) * rstd * gg + be;
      *reinterpret_cast<fx4*>(out + (size_t)row * 512 + i4 * 4) = y;
    }
  }
}

// ---------------- launcher ------------------------------------------------------
extern "C" void kernel_launch(void* const* d_in, const int* in_sizes, int n_in,
                              void* d_out, int out_size, void* d_ws, size_t ws_size,
                              hipStream_t stream) {
  const float* q    = (const float*)d_in[0];
  const float* k    = (const float*)d_in[1];
  const float* v    = (const float*)d_in[2];
  const int*   mask = (const int*)d_in[3];
  const float* gate = (const float*)d_in[4];
  const float* w_qs = (const float*)d_in[5];
  const float* b_qs = (const float*)d_in[6];
  const float* w_ks = (const float*)d_in[7];
  const float* b_ks = (const float*)d_in[8];
  const float* w_vs = (const float*)d_in[9];
  const float* b_vs = (const float*)d_in[10];
  const float* w_fc = (const float*)d_in[11];
  const float* b_fc = (const float*)d_in[12];
  const float* ln_g = (const float*)d_in[13];
  const float* ln_b = (const float*)d_in[14];
  float* out = (float*)d_out;

  char* ws = (char*)d_ws;
  unsigned short* Qb = (unsigned short*)(ws);                        //  4 MB
  unsigned short* Kb = (unsigned short*)(ws + 4194304);              //  4 MB
  unsigned short* Vt = (unsigned short*)(ws + 8388608);              //  4 MB
  unsigned short* Ob = (unsigned short*)(ws + 12582912);             //  4 MB
  unsigned short* Wb = (unsigned short*)(ws + 16777216);             //  2 MB (4 x 512KB)
  unsigned long long* mbits = (unsigned long long*)(ws + 18874368);  //  1 MB

  float* attn = out + 2097152;  // [B,H,L,L] fp32, part of output

  k_w2bf<<<dim3(256, 4), 256, 0, stream>>>(w_qs, w_ks, w_vs, w_fc, Wb);
  k_maskpack<<<32768, 256, 0, stream>>>(mask, mbits);
  k_proj2<<<dim3(64, 8, 3), 256, 0, stream>>>(q, k, v, Wb, b_qs, b_ks, b_vs,
                                              Qb, Kb, Vt);
  k_score<<<dim3(128, 16), 512, 0, stream>>>(Qb, Kb, gate, mbits, attn);
  k_pv<<<dim3(64, 16), 256, 0, stream>>>(attn, Vt, Ob);
  k_fc_ln<<<256, 256, 0, stream>>>(Ob, Wb + 786432, b_fc, q, ln_g, ln_b, out);
}